// Round 9
// baseline (577.438 us; speedup 1.0000x reference)
//
#include <hip/hip_runtime.h>
#include <hip/hip_bf16.h>

typedef __attribute__((ext_vector_type(8))) short bf16x8;
typedef __attribute__((ext_vector_type(4))) float f32x4;
typedef unsigned int uint32;

#define F 128
#define HOPS 5
#define LDS_STRIDE 68

__device__ __forceinline__ float b2f(__hip_bfloat16 h) { return __bfloat162float(h); }
__device__ __forceinline__ __hip_bfloat16 f2b(float f) { return __float2bfloat16(f); }

__device__ __forceinline__ float load_in(const void* p, size_t i, int isbf) {
    return isbf ? __bfloat162float(((const __hip_bfloat16*)p)[i]) : ((const float*)p)[i];
}

__device__ __forceinline__ float bflo(uint32 u) { union { uint32 i; float f; } v; v.i = u << 16; return v.f; }
__device__ __forceinline__ float bfhi(uint32 u) { union { uint32 i; float f; } v; v.i = u & 0xffff0000u; return v.f; }
__device__ __forceinline__ uint32 packbf2(float a, float b) {
    __hip_bfloat16 ha = f2b(a), hb = f2b(b);
    unsigned short ua = *(unsigned short*)&ha, ub = *(unsigned short*)&hb;
    return ((uint32)ub << 16) | ua;
}

__device__ __forceinline__ float edge_dot(uint4 gv, const float* ftf, const float* at) {
    float acc = 0.f;
    uint32 us[4] = {gv.x, gv.y, gv.z, gv.w};
    #pragma unroll
    for (int k = 0; k < 4; ++k) {
        float f0 = bflo(us[k]) * ftf[2 * k];
        float f1 = bfhi(us[k]) * ftf[2 * k + 1];
        f0 = fmaxf(f0, 0.2f * f0);
        f1 = fmaxf(f1, 0.2f * f1);
        acc = fmaf(f0, at[2 * k], acc);
        acc = fmaf(f1, at[2 * k + 1], acc);
    }
    return acc;
}

// ---------------- dtype detection ----------------
__global__ void detect_k(const uint32* __restrict__ w, int* flag) {
    __shared__ int cnt[256];
    int t = threadIdx.x;
    uint32 x = w[t * 97];
    int e_low = (x >> 7) & 0xFF;
    cnt[t] = (e_low >= 110 && e_low <= 135) ? 1 : 0;
    __syncthreads();
    for (int s = 128; s > 0; s >>= 1) {
        if (t < s) cnt[t] += cnt[t + s];
        __syncthreads();
    }
    if (t == 0) flag[0] = (cnt[0] >= 160) ? 1 : 0;
}

// ---------------- fused weight/bias conversion ----------------
__global__ void cvt_all_k(const void* __restrict__ w_head, const void* __restrict__ w_tail,
                          const void* __restrict__ w_ent, const void* __restrict__ ff_w1,
                          const void* __restrict__ ff_w2, const void* __restrict__ attn,
                          const void* __restrict__ ff_b1, const void* __restrict__ ff_b2,
                          const int* __restrict__ flag,
                          __hip_bfloat16* __restrict__ wblob, float* __restrict__ fblob) {
    int i = blockIdx.x * blockDim.x + threadIdx.x;
    int isbf = flag[0];
    if (i < 180224) {
        const void* srcp; int j;
        if (i < 16384)       { srcp = w_head; j = i; }
        else if (i < 32768)  { srcp = w_tail; j = i - 16384; }
        else if (i < 49152)  { srcp = w_ent;  j = i - 32768; }
        else if (i < 114688) { srcp = ff_w1;  j = i - 49152; }
        else                 { srcp = ff_w2;  j = i - 114688; }
        wblob[i] = f2b(load_in(srcp, j, isbf));
    } else if (i < 180992) {
        int k = i - 180224;
        const void* srcp; int j;
        if (k < 128)      { srcp = attn;  j = k; }
        else if (k < 640) { srcp = ff_b1; j = k - 128; }
        else              { srcp = ff_b2; j = k - 640; }
        fblob[k] = load_in(srcp, j, isbf);
    }
}

// ---------------- graph build ----------------
__global__ void degree_k(const int* __restrict__ src, const int* __restrict__ dst,
                         int* in_cnt, int* out_cnt, int E) {
    int i = blockIdx.x * blockDim.x + threadIdx.x;
    if (i < E) {
        atomicAdd(&in_cnt[dst[i]], 1);
        atomicAdd(&out_cnt[src[i]], 1);
    }
}

__global__ void scan1_k(const int* __restrict__ cnt, int* partial, int* blk_sum, int N) {
    __shared__ int sh[256];
    int t = threadIdx.x;
    int i = blockIdx.x * 256 + t;
    int c = (i < N) ? cnt[i] : 0;
    sh[t] = c;
    __syncthreads();
    for (int o = 1; o < 256; o <<= 1) {
        int v = (t >= o) ? sh[t - o] : 0;
        __syncthreads();
        sh[t] += v;
        __syncthreads();
    }
    if (i < N) partial[i] = sh[t] - c;
    if (t == 255) blk_sum[blockIdx.x] = sh[255];
}

__global__ void scan2_k(const int* __restrict__ blk_sum, int* blk_off, int nb,
                        int* row_ptr, int N) {
    __shared__ int sh[256];
    int t = threadIdx.x;
    if (nb <= 256) {
        int v = (t < nb) ? blk_sum[t] : 0;
        sh[t] = v;
        __syncthreads();
        for (int o = 1; o < 256; o <<= 1) {
            int u = (t >= o) ? sh[t - o] : 0;
            __syncthreads();
            sh[t] += u;
            __syncthreads();
        }
        if (t < nb) blk_off[t] = sh[t] - v;
        if (t == 255) row_ptr[N] = sh[255];
    } else if (t == 0) {
        int run = 0;
        for (int b = 0; b < nb; ++b) { blk_off[b] = run; run += blk_sum[b]; }
        row_ptr[N] = run;
    }
}

__global__ void scan3_norms_k(const int* __restrict__ partial, const int* __restrict__ blk_off,
                              const int* __restrict__ cnt_in, const int* __restrict__ cnt_out,
                              int* row_ptr, float* head_norm, float* tail_norm,
                              float* log_in, int N) {
    int i = blockIdx.x * 256 + threadIdx.x;
    if (i >= N) return;
    row_ptr[i] = partial[i] + blk_off[blockIdx.x];
    float id = fmaxf((float)cnt_in[i], 1.0f);
    float od = fmaxf((float)cnt_out[i], 1.0f);
    head_norm[i] = rsqrtf(od);
    tail_norm[i] = sqrtf(id);
    log_in[i] = log1pf(id);
}

__global__ void scatter_k(const int* __restrict__ src, const int* __restrict__ dst,
                          const int* __restrict__ row_ptr, int* cursor,
                          int* csr_src, int E) {
    int i = blockIdx.x * blockDim.x + threadIdx.x;
    if (i < E) {
        int d = dst[i];
        int p = row_ptr[d] + atomicAdd(&cursor[d], 1);
        csr_src[p] = src[i];
    }
}

// ---------------- LayerNorms ----------------
__global__ void ln1_k(const void* __restrict__ x, const void* __restrict__ g,
                      const void* __restrict__ b, const int* __restrict__ flag,
                      __hip_bfloat16* __restrict__ y, int N) {
    int w = blockIdx.x * (blockDim.x >> 6) + (threadIdx.x >> 6);
    if (w >= N) return;
    int isbf = flag[0];
    int t = threadIdx.x & 63;
    float v0 = load_in(x, (size_t)w * F + t, isbf);
    float v1 = load_in(x, (size_t)w * F + t + 64, isbf);
    float s = v0 + v1, sq = v0 * v0 + v1 * v1;
    for (int m = 1; m < 64; m <<= 1) { s += __shfl_xor(s, m, 64); sq += __shfl_xor(sq, m, 64); }
    float mu = s * (1.0f / F);
    float var = fmaxf(sq * (1.0f / F) - mu * mu, 0.0f);
    float r = rsqrtf(var + 1e-5f);
    y[(size_t)w * F + t]      = f2b((v0 - mu) * r * load_in(g, t, isbf) + load_in(b, t, isbf));
    y[(size_t)w * F + t + 64] = f2b((v1 - mu) * r * load_in(g, t + 64, isbf) + load_in(b, t + 64, isbf));
}

__global__ void ln2_k(const float* __restrict__ x, const void* __restrict__ g,
                      const void* __restrict__ b, const int* __restrict__ flag,
                      __hip_bfloat16* __restrict__ y, int N) {
    int w = blockIdx.x * (blockDim.x >> 6) + (threadIdx.x >> 6);
    if (w >= N) return;
    int isbf = flag[0];
    int t = threadIdx.x & 63;
    float v0 = x[(size_t)w * F + t], v1 = x[(size_t)w * F + t + 64];
    float s = v0 + v1, sq = v0 * v0 + v1 * v1;
    for (int m = 1; m < 64; m <<= 1) { s += __shfl_xor(s, m, 64); sq += __shfl_xor(sq, m, 64); }
    float mu = s * (1.0f / F);
    float var = fmaxf(sq * (1.0f / F) - mu * mu, 0.0f);
    float r = rsqrtf(var + 1e-5f);
    y[(size_t)w * F + t]      = f2b((v0 - mu) * r * load_in(g, t, isbf) + load_in(b, t, isbf));
    y[(size_t)w * F + t + 64] = f2b((v1 - mu) * r * load_in(g, t + 64, isbf) + load_in(b, t + 64, isbf));
}

// ---------------- projection GEMM (64Mx64N, LDS epilogue, no RFO) ----------------
__global__ void proj_gemm_k(const __hip_bfloat16* __restrict__ X,
                            const __hip_bfloat16* __restrict__ Wh,
                            const __hip_bfloat16* __restrict__ Wt,
                            const __hip_bfloat16* __restrict__ We,
                            const float* __restrict__ head_norm,
                            __hip_bfloat16* __restrict__ fh,
                            __hip_bfloat16* __restrict__ ft,
                            uint32* __restrict__ fe_bf, int N) {
    __shared__ float lds[64 * LDS_STRIDE];
    int tid = threadIdx.x;
    int wv = tid >> 6, lane = tid & 63;
    int lr = lane & 15, quad = lane >> 4;
    int bm = blockIdx.x * 64;
    int g = blockIdx.y;
    int wsel = g >> 1;
    const __hip_bfloat16* W = (wsel == 0) ? Wh : (wsel == 1) ? Wt : We;
    int wcb = (g & 1) * 64;
    int row_a = bm + wv * 16 + lr;
    if (row_a >= N) row_a = N - 1;
    f32x4 acc0 = {0,0,0,0}, acc1 = {0,0,0,0}, acc2 = {0,0,0,0}, acc3 = {0,0,0,0};
    const __hip_bfloat16* ar = X + (size_t)row_a * F + quad * 8;
    const __hip_bfloat16* br = W + (size_t)(wcb + lr) * F + quad * 8;
    for (int ks = 0; ks < 4; ++ks) {
        bf16x8 a = *reinterpret_cast<const bf16x8*>(ar + ks * 32);
        bf16x8 b0 = *reinterpret_cast<const bf16x8*>(br + ks * 32);
        bf16x8 b1 = *reinterpret_cast<const bf16x8*>(br + 16 * F + ks * 32);
        bf16x8 b2 = *reinterpret_cast<const bf16x8*>(br + 32 * F + ks * 32);
        bf16x8 b3 = *reinterpret_cast<const bf16x8*>(br + 48 * F + ks * 32);
        acc0 = __builtin_amdgcn_mfma_f32_16x16x32_bf16(a, b0, acc0, 0, 0, 0);
        acc1 = __builtin_amdgcn_mfma_f32_16x16x32_bf16(a, b1, acc1, 0, 0, 0);
        acc2 = __builtin_amdgcn_mfma_f32_16x16x32_bf16(a, b2, acc2, 0, 0, 0);
        acc3 = __builtin_amdgcn_mfma_f32_16x16x32_bf16(a, b3, acc3, 0, 0, 0);
    }
    int rl = wv * 16 + quad * 4;
#pragma unroll
    for (int r = 0; r < 4; ++r) {
        lds[(rl + r) * LDS_STRIDE + lr]      = acc0[r];
        lds[(rl + r) * LDS_STRIDE + 16 + lr] = acc1[r];
        lds[(rl + r) * LDS_STRIDE + 32 + lr] = acc2[r];
        lds[(rl + r) * LDS_STRIDE + 48 + lr] = acc3[r];
    }
    __syncthreads();
    int tr = tid >> 4, tc = (tid & 15) * 4;
#pragma unroll
    for (int p = 0; p < 4; ++p) {
        int row_l = p * 16 + tr;
        int grow = bm + row_l;
        if (grow >= N) continue;
        float4 v = *(const float4*)&lds[row_l * LDS_STRIDE + tc];
        float hn = head_norm[grow];
        v.x *= hn; v.y *= hn; v.z *= hn; v.w *= hn;
        size_t idx = (size_t)grow * F + wcb + tc;
        uint2 u; u.x = packbf2(v.x, v.y); u.y = packbf2(v.z, v.w);
        __hip_bfloat16* dstp = (wsel == 0) ? fh : (wsel == 1) ? ft : (__hip_bfloat16*)fe_bf;
        *(uint2*)&dstp[idx] = u;
    }
}

// ---------------- fused edge attention + softmax (16 lanes/edge, 4 edges/iter) ----------------
__global__ void attn_soft_k(const int* __restrict__ csr_src, const int* __restrict__ row_ptr,
                            const uint32* __restrict__ fh2, const uint32* __restrict__ ft2,
                            const float* __restrict__ attn_f, const float* __restrict__ log_in,
                            float* __restrict__ e_buf, float* __restrict__ inv_arr, int N) {
    int w = blockIdx.x * (blockDim.x >> 6) + (threadIdx.x >> 6);
    if (w >= N) return;
    int t = threadIdx.x & 63;
    int g = t >> 4, j = t & 15;
    int b = row_ptr[w], e = row_ptr[w + 1];
    uint4 fr = ((const uint4*)ft2)[(size_t)w * 16 + j];
    float ftf[8] = {bflo(fr.x), bfhi(fr.x), bflo(fr.y), bfhi(fr.y),
                    bflo(fr.z), bfhi(fr.z), bflo(fr.w), bfhi(fr.w)};
    float at[8];
#pragma unroll
    for (int k = 0; k < 8; ++k) at[k] = attn_f[8 * j + k];
    float scale = log_in[w] * (1.0f / 16.0f);
    float m = -1e30f;
    for (int p0 = b; p0 < e; p0 += 8) {
        int pa = p0 + g, pb = p0 + 4 + g;
        bool oka = pa < e, okb = pb < e;
        int sa = csr_src[oka ? pa : b];
        int sb = csr_src[okb ? pb : b];
        uint4 ga = ((const uint4*)fh2)[(size_t)sa * 16 + j];
        uint4 gb = ((const uint4*)fh2)[(size_t)sb * 16 + j];
        float ra = edge_dot(ga, ftf, at);
        float rb = edge_dot(gb, ftf, at);
        ra += __shfl_xor(ra, 1, 64);
        rb += __shfl_xor(rb, 1, 64);
        float la = ra * scale, lb = rb * scale;
        if (oka) { if (!(j & 1)) e_buf[(size_t)pa * 8 + (j >> 1)] = la; m = fmaxf(m, la); }
        if (okb) { if (!(j & 1)) e_buf[(size_t)pb * 8 + (j >> 1)] = lb; m = fmaxf(m, lb); }
    }
    m = fmaxf(m, __shfl_xor(m, 16, 64));
    m = fmaxf(m, __shfl_xor(m, 32, 64));
    float mh = __shfl(m, (t & 7) * 2, 64);
    float sum = 0.f;
    for (size_t base = (size_t)b * 8 + t; base < (size_t)e * 8; base += 64) {
        float ex = expf(e_buf[base] - mh);
        e_buf[base] = ex;
        sum += ex;
    }
    sum += __shfl_xor(sum, 8, 64);
    sum += __shfl_xor(sum, 16, 64);
    sum += __shfl_xor(sum, 32, 64);
    float inv = 1.0f / fmaxf(sum, 1e-30f);
    if (t < 8) inv_arr[(size_t)w * 8 + t] = inv;
}

// ---------------- diffusion hop (32 lanes/edge, 2 edges/iter, batch 8) ----------------
__global__ void hop_k(const uint32* __restrict__ gsrc2, const float* __restrict__ e_exp,
                      const float* __restrict__ inv_arr,
                      const int* __restrict__ csr_src, const int* __restrict__ row_ptr,
                      const float* __restrict__ tail_norm, const float* __restrict__ head_norm,
                      const uint32* __restrict__ fe_bf, const void* __restrict__ feat,
                      const int* __restrict__ flag,
                      uint32* __restrict__ out_bf, float* __restrict__ out_f32,
                      int last, int N) {
    int w = blockIdx.x * (blockDim.x >> 6) + (threadIdx.x >> 6);
    if (w >= N) return;
    int t = threadIdx.x & 63;
    int sl = t >> 5, l = t & 31;
    int h = l >> 2;
    int b = row_ptr[w], e = row_ptr[w + 1];
    float inv = inv_arr[(size_t)w * 8 + h];
    float a0 = 0.f, a1 = 0.f, a2 = 0.f, a3 = 0.f;
    int p = b;
    for (; p + 8 <= e; p += 8) {
        int pe[4]; int s[4]; float av[4]; uint2 gg[4];
#pragma unroll
        for (int i = 0; i < 4; ++i) pe[i] = p + 2 * i + sl;
#pragma unroll
        for (int i = 0; i < 4; ++i) s[i] = csr_src[pe[i]];
#pragma unroll
        for (int i = 0; i < 4; ++i) av[i] = e_exp[(size_t)pe[i] * 8 + h];
#pragma unroll
        for (int i = 0; i < 4; ++i) gg[i] = ((const uint2*)gsrc2)[(size_t)s[i] * 32 + l];
#pragma unroll
        for (int i = 0; i < 4; ++i) {
            a0 += bflo(gg[i].x) * av[i]; a1 += bfhi(gg[i].x) * av[i];
            a2 += bflo(gg[i].y) * av[i]; a3 += bfhi(gg[i].y) * av[i];
        }
    }
    if (p < e) {
        int pe[4]; int s[4]; float av[4]; uint2 gg[4]; bool ok[4];
#pragma unroll
        for (int i = 0; i < 4; ++i) {
            int q = p + 2 * i + sl;
            ok[i] = q < e;
            pe[i] = ok[i] ? q : b;
        }
#pragma unroll
        for (int i = 0; i < 4; ++i) s[i] = csr_src[pe[i]];
#pragma unroll
        for (int i = 0; i < 4; ++i) av[i] = ok[i] ? e_exp[(size_t)pe[i] * 8 + h] : 0.f;
#pragma unroll
        for (int i = 0; i < 4; ++i) gg[i] = ((const uint2*)gsrc2)[(size_t)s[i] * 32 + l];
#pragma unroll
        for (int i = 0; i < 4; ++i) {
            a0 += bflo(gg[i].x) * av[i]; a1 += bfhi(gg[i].x) * av[i];
            a2 += bflo(gg[i].y) * av[i]; a3 += bfhi(gg[i].y) * av[i];
        }
    }
    a0 += __shfl_xor(a0, 32, 64);
    a1 += __shfl_xor(a1, 32, 64);
    a2 += __shfl_xor(a2, 32, 64);
    a3 += __shfl_xor(a3, 32, 64);
    if (t < 32) {
        float tl = tail_norm[w] * 0.9f * inv;
        uint2 feu = ((const uint2*)fe_bf)[(size_t)w * 32 + l];
        float r0 = tl * a0 + 0.1f * bflo(feu.x);
        float r1 = tl * a1 + 0.1f * bfhi(feu.x);
        float r2 = tl * a2 + 0.1f * bflo(feu.y);
        float r3 = tl * a3 + 0.1f * bfhi(feu.y);
        if (last) {
            int isbf = flag[0];
            float4 o;
            if (isbf) {
                uint2 fu = ((const uint2*)feat)[(size_t)w * 32 + l];
                o.x = r0 + bflo(fu.x); o.y = r1 + bfhi(fu.x);
                o.z = r2 + bflo(fu.y); o.w = r3 + bfhi(fu.y);
            } else {
                float4 fv = ((const float4*)feat)[(size_t)w * 32 + l];
                o.x = r0 + fv.x; o.y = r1 + fv.y; o.z = r2 + fv.z; o.w = r3 + fv.w;
            }
            ((float4*)out_f32)[(size_t)w * 32 + l] = o;
        } else {
            float hn = head_norm[w];
            uint2 u;
            u.x = packbf2(r0 * hn, r1 * hn);
            u.y = packbf2(r2 * hn, r3 * hn);
            ((uint2*)out_bf)[(size_t)w * 32 + l] = u;
        }
    }
}

// ---------------- FUSED FFN v2: 512 thr, 8 waves, chunk-split across wave halves ----------------
// waves 0-3: chunks 0-3; waves 4-7: chunks 4-7. Same 16-row groups; partial sums merged in LDS.
#define TB_STRIDE 72
__global__ __launch_bounds__(512, 2)
void ffn_fused_k(const __hip_bfloat16* __restrict__ Y, const __hip_bfloat16* __restrict__ W1,
                 const __hip_bfloat16* __restrict__ W2, const float* __restrict__ b1f,
                 const float* __restrict__ b2f, const float* __restrict__ rst,
                 const int* __restrict__ flag, void* __restrict__ out, int N) {
    __shared__ __align__(16) float eps[64 * 132];                       // 33792 B
    __shared__ __align__(16) __hip_bfloat16 tb[8 * 16 * TB_STRIDE];     // 18432 B
    int tid = threadIdx.x;
    int wv = tid >> 6, lane = tid & 63;
    int rw = wv & 3, cg = wv >> 2;
    int lr = lane & 15, quad = lane >> 4;
    int bm = blockIdx.x * 64;
    int row_a = bm + rw * 16 + lr;
    if (row_a >= N) row_a = N - 1;
    bf16x8 ay[4];
    {
        const __hip_bfloat16* yr = Y + (size_t)row_a * F + quad * 8;
#pragma unroll
        for (int ks = 0; ks < 4; ++ks) ay[ks] = *reinterpret_cast<const bf16x8*>(yr + ks * 32);
    }
    // preload b1 biases for this wave's 4 chunks
    float b1v[4][4];
#pragma unroll
    for (int cc = 0; cc < 4; ++cc)
#pragma unroll
        for (int j = 0; j < 4; ++j)
            b1v[cc][j] = b1f[(cg * 4 + cc) * 64 + 16 * j + lr];
    f32x4 o[8];
#pragma unroll
    for (int j = 0; j < 8; ++j) o[j] = (f32x4){0,0,0,0};
    __hip_bfloat16* tbuf = tb + wv * (16 * TB_STRIDE);
    for (int cc = 0; cc < 4; ++cc) {
        int nb0 = (cg * 4 + cc) * 64;
        // phase A: T1c = relu(Y @ W1c^T + b1c), 16 rows x 64 cols per wave
        f32x4 t0 = {0,0,0,0}, t1 = {0,0,0,0}, t2 = {0,0,0,0}, t3 = {0,0,0,0};
        const __hip_bfloat16* w1r = W1 + (size_t)(nb0 + lr) * F + quad * 8;
#pragma unroll
        for (int ks = 0; ks < 4; ++ks) {
            bf16x8 b0 = *reinterpret_cast<const bf16x8*>(w1r + ks * 32);
            bf16x8 b1 = *reinterpret_cast<const bf16x8*>(w1r + 16 * F + ks * 32);
            bf16x8 b2 = *reinterpret_cast<const bf16x8*>(w1r + 32 * F + ks * 32);
            bf16x8 b3 = *reinterpret_cast<const bf16x8*>(w1r + 48 * F + ks * 32);
            t0 = __builtin_amdgcn_mfma_f32_16x16x32_bf16(ay[ks], b0, t0, 0, 0, 0);
            t1 = __builtin_amdgcn_mfma_f32_16x16x32_bf16(ay[ks], b1, t1, 0, 0, 0);
            t2 = __builtin_amdgcn_mfma_f32_16x16x32_bf16(ay[ks], b2, t2, 0, 0, 0);
            t3 = __builtin_amdgcn_mfma_f32_16x16x32_bf16(ay[ks], b3, t3, 0, 0, 0);
        }
        {
            f32x4 ts[4] = {t0, t1, t2, t3};
#pragma unroll
            for (int j = 0; j < 4; ++j) {
                float bias = b1v[cc][j];
#pragma unroll
                for (int r = 0; r < 4; ++r) {
                    float v = fmaxf(ts[j][r] + bias, 0.f);
                    tbuf[(quad * 4 + r) * TB_STRIDE + j * 16 + lr] = f2b(v);
                }
            }
        }
        // phase B: o += T1c @ W2c^T  (A from wave-private LDS, B L2-hot)
#pragma unroll
        for (int ks2 = 0; ks2 < 2; ++ks2) {
            bf16x8 at = *reinterpret_cast<const bf16x8*>(&tbuf[lr * TB_STRIDE + ks2 * 32 + quad * 8]);
            const __hip_bfloat16* w2r = W2 + (size_t)lr * 512 + nb0 + ks2 * 32 + quad * 8;
#pragma unroll
            for (int j2 = 0; j2 < 8; ++j2) {
                bf16x8 bb = *reinterpret_cast<const bf16x8*>(w2r + (size_t)(j2 * 16) * 512);
                o[j2] = __builtin_amdgcn_mfma_f32_16x16x32_bf16(at, bb, o[j2], 0, 0, 0);
            }
        }
    }
    // two-phase epilogue merge: cg0 writes, cg1 adds
    int rl = rw * 16 + quad * 4;
    __syncthreads();
    if (cg == 0) {
#pragma unroll
        for (int j = 0; j < 8; ++j)
#pragma unroll
            for (int r = 0; r < 4; ++r)
                eps[(rl + r) * 132 + j * 16 + lr] = o[j][r];
    }
    __syncthreads();
    if (cg == 1) {
#pragma unroll
        for (int j = 0; j < 8; ++j)
#pragma unroll
            for (int r = 0; r < 4; ++r)
                eps[(rl + r) * 132 + j * 16 + lr] += o[j][r];
    }
    __syncthreads();
    int isbf = flag[0];
#pragma unroll
    for (int p = 0; p < 4; ++p) {
        int idx = p * 2048 + tid * 4;
        int row_l = idx >> 7, col = idx & 127;
        int grow = bm + row_l;
        if (grow >= N) continue;
        float4 v = *(const float4*)&eps[row_l * 132 + col];
        float4 bias = *(const float4*)&b2f[col];
        float4 rv = *(const float4*)&rst[(size_t)grow * F + col];
        v.x += bias.x + rv.x; v.y += bias.y + rv.y;
        v.z += bias.z + rv.z; v.w += bias.w + rv.w;
        size_t gidx = (size_t)grow * F + col;
        if (isbf) {
            uint2 u; u.x = packbf2(v.x, v.y); u.y = packbf2(v.z, v.w);
            *(uint2*)&((__hip_bfloat16*)out)[gidx] = u;
        } else {
            *(float4*)&((float*)out)[gidx] = v;
        }
    }
}

extern "C" void kernel_launch(void* const* d_in, const int* in_sizes, int n_in,
                              void* d_out, int out_size, void* d_ws, size_t ws_size,
                              hipStream_t stream) {
    if (n_in < 15) return;
    const void* feat = d_in[0];
    const int* src = (const int*)d_in[1];
    const int* dst = (const int*)d_in[2];
    const void* w_head = d_in[3];
    const void* w_tail = d_in[4];
    const void* w_ent  = d_in[5];
    const void* attn   = d_in[6];
    const void* ln1_g  = d_in[7];
    const void* ln1_b  = d_in[8];
    const void* ln2_g  = d_in[9];
    const void* ln2_b  = d_in[10];
    const void* ff_w1  = d_in[11];
    const void* ff_b1  = d_in[12];
    const void* ff_w2  = d_in[13];
    const void* ff_b2  = d_in[14];

    const int N = in_sizes[0] / F;
    const int E = in_sizes[1];
    (void)out_size;

    char* base = (char*)d_ws;
    size_t off = 0;
    auto alloc = [&](size_t bytes) -> void* {
        void* r = base + off;
        off += (bytes + 255) & ~(size_t)255;
        return r;
    };
    int* cnt3      = (int*)alloc((size_t)3 * N * 4);
    int* in_cnt = cnt3, * out_cnt = cnt3 + N, * cursor = cnt3 + 2 * N;
    int* row_ptr   = (int*)alloc((size_t)(N + 1) * 4);
    int* partial   = (int*)alloc((size_t)N * 4);
    int* blk_sum   = (int*)alloc((size_t)1024 * 4);
    int* blk_off   = (int*)alloc((size_t)1024 * 4);
    int* flag      = (int*)alloc(256);
    float* head_norm = (float*)alloc((size_t)N * 4);
    float* tail_norm = (float*)alloc((size_t)N * 4);
    float* log_in    = (float*)alloc((size_t)N * 4);
    float* inv_arr   = (float*)alloc((size_t)N * 8 * 4);
    int* csr_src   = (int*)alloc((size_t)E * 4);
    __hip_bfloat16* wh_bf = (__hip_bfloat16*)alloc((size_t)F * F * 2);
    __hip_bfloat16* wt_bf = (__hip_bfloat16*)alloc((size_t)F * F * 2);
    __hip_bfloat16* we_bf = (__hip_bfloat16*)alloc((size_t)F * F * 2);
    __hip_bfloat16* w1_bf = (__hip_bfloat16*)alloc((size_t)512 * F * 2);
    __hip_bfloat16* w2_bf = (__hip_bfloat16*)alloc((size_t)F * 512 * 2);
    float* attn_f    = (float*)alloc((size_t)F * 4);
    float* b1f       = (float*)alloc((size_t)512 * 4);
    float* b2f_      = (float*)alloc((size_t)F * 4);
    __hip_bfloat16* x_bf = (__hip_bfloat16*)alloc((size_t)N * F * 2);
    __hip_bfloat16* fh   = (__hip_bfloat16*)alloc((size_t)N * F * 2);
    __hip_bfloat16* ftb  = (__hip_bfloat16*)alloc((size_t)N * F * 2);
    float* e_a = (float*)alloc((size_t)E * 8 * 4);
    uint32* fe_bf = (uint32*)alloc((size_t)N * F * 2);
    uint32* hA_bf = (uint32*)alloc((size_t)N * F * 2);
    uint32* hB_bf = (uint32*)alloc((size_t)N * F * 2);
    float* rst = (float*)alloc((size_t)N * F * 4);
    __hip_bfloat16* y_bf = (__hip_bfloat16*)hA_bf;
    if (off > ws_size) return;

    const int Mb = (N + 63) / 64;
    const int nodeBlocks = (N + 3) / 4;
    const int nb = (N + 255) / 256;

    detect_k<<<1, 256, 0, stream>>>((const uint32*)feat, flag);
    cvt_all_k<<<(180992 + 255) / 256, 256, 0, stream>>>(w_head, w_tail, w_ent, ff_w1, ff_w2,
                                                        attn, ff_b1, ff_b2, flag, wh_bf, attn_f);

    hipMemsetAsync(cnt3, 0, (size_t)3 * N * 4, stream);
    degree_k<<<(E + 255) / 256, 256, 0, stream>>>(src, dst, in_cnt, out_cnt, E);
    scan1_k<<<nb, 256, 0, stream>>>(in_cnt, partial, blk_sum, N);
    scan2_k<<<1, 256, 0, stream>>>(blk_sum, blk_off, nb, row_ptr, N);
    scan3_norms_k<<<nb, 256, 0, stream>>>(partial, blk_off, in_cnt, out_cnt,
                                          row_ptr, head_norm, tail_norm, log_in, N);
    scatter_k<<<(E + 255) / 256, 256, 0, stream>>>(src, dst, row_ptr, cursor, csr_src, E);

    ln1_k<<<nodeBlocks, 256, 0, stream>>>(feat, ln1_g, ln1_b, flag, x_bf, N);
    proj_gemm_k<<<dim3(Mb, 6), 256, 0, stream>>>(x_bf, wh_bf, wt_bf, we_bf, head_norm,
                                                 fh, ftb, fe_bf, N);

    attn_soft_k<<<nodeBlocks, 256, 0, stream>>>(csr_src, row_ptr, (const uint32*)fh,
                                                (const uint32*)ftb, attn_f, log_in,
                                                e_a, inv_arr, N);

    const uint32* gsrc = fe_bf;
    uint32* bufs[2] = {hA_bf, hB_bf};
    for (int hop = 0; hop < HOPS; ++hop) {
        int last = (hop == HOPS - 1);
        uint32* dst_bf = last ? nullptr : bufs[hop & 1];
        hop_k<<<nodeBlocks, 256, 0, stream>>>(gsrc, e_a, inv_arr, csr_src, row_ptr, tail_norm,
                                              head_norm, fe_bf, feat, flag, dst_bf, rst, last, N);
        if (!last) gsrc = dst_bf;
    }

    ln2_k<<<nodeBlocks, 256, 0, stream>>>(rst, ln2_g, ln2_b, flag, y_bf, N);
    ffn_fused_k<<<Mb, 512, 0, stream>>>(y_bf, w1_bf, w2_bf, b1f, b2f_, rst, flag, d_out, N);
}

// Round 10
// 472.389 us; speedup vs baseline: 1.2224x; 1.2224x over previous
//
#include <hip/hip_runtime.h>
#include <hip/hip_bf16.h>

typedef __attribute__((ext_vector_type(8))) short bf16x8;
typedef __attribute__((ext_vector_type(4))) float f32x4;
typedef unsigned int uint32;

#define F 128
#define HOPS 5
#define LDS_STRIDE 68
#define W1_STRIDE 136   // 128 + 8 pad (bf16 elems)
#define W2_STRIDE 72    // 64 + 8 pad
#define TB_STRIDE 72

__device__ __forceinline__ float b2f(__hip_bfloat16 h) { return __bfloat162float(h); }
__device__ __forceinline__ __hip_bfloat16 f2b(float f) { return __float2bfloat16(f); }

__device__ __forceinline__ float load_in(const void* p, size_t i, int isbf) {
    return isbf ? __bfloat162float(((const __hip_bfloat16*)p)[i]) : ((const float*)p)[i];
}

__device__ __forceinline__ float bflo(uint32 u) { union { uint32 i; float f; } v; v.i = u << 16; return v.f; }
__device__ __forceinline__ float bfhi(uint32 u) { union { uint32 i; float f; } v; v.i = u & 0xffff0000u; return v.f; }
__device__ __forceinline__ uint32 packbf2(float a, float b) {
    __hip_bfloat16 ha = f2b(a), hb = f2b(b);
    unsigned short ua = *(unsigned short*)&ha, ub = *(unsigned short*)&hb;
    return ((uint32)ub << 16) | ua;
}

__device__ __forceinline__ float edge_dot(uint4 gv, const float* ftf, const float* at) {
    float acc = 0.f;
    uint32 us[4] = {gv.x, gv.y, gv.z, gv.w};
    #pragma unroll
    for (int k = 0; k < 4; ++k) {
        float f0 = bflo(us[k]) * ftf[2 * k];
        float f1 = bfhi(us[k]) * ftf[2 * k + 1];
        f0 = fmaxf(f0, 0.2f * f0);
        f1 = fmaxf(f1, 0.2f * f1);
        acc = fmaf(f0, at[2 * k], acc);
        acc = fmaf(f1, at[2 * k + 1], acc);
    }
    return acc;
}

// ---------------- dtype detection ----------------
__global__ void detect_k(const uint32* __restrict__ w, int* flag) {
    __shared__ int cnt[256];
    int t = threadIdx.x;
    uint32 x = w[t * 97];
    int e_low = (x >> 7) & 0xFF;
    cnt[t] = (e_low >= 110 && e_low <= 135) ? 1 : 0;
    __syncthreads();
    for (int s = 128; s > 0; s >>= 1) {
        if (t < s) cnt[t] += cnt[t + s];
        __syncthreads();
    }
    if (t == 0) flag[0] = (cnt[0] >= 160) ? 1 : 0;
}

// ---------------- fused weight/bias conversion ----------------
__global__ void cvt_all_k(const void* __restrict__ w_head, const void* __restrict__ w_tail,
                          const void* __restrict__ w_ent, const void* __restrict__ ff_w1,
                          const void* __restrict__ ff_w2, const void* __restrict__ attn,
                          const void* __restrict__ ff_b1, const void* __restrict__ ff_b2,
                          const int* __restrict__ flag,
                          __hip_bfloat16* __restrict__ wblob, float* __restrict__ fblob) {
    int i = blockIdx.x * blockDim.x + threadIdx.x;
    int isbf = flag[0];
    if (i < 180224) {
        const void* srcp; int j;
        if (i < 16384)       { srcp = w_head; j = i; }
        else if (i < 32768)  { srcp = w_tail; j = i - 16384; }
        else if (i < 49152)  { srcp = w_ent;  j = i - 32768; }
        else if (i < 114688) { srcp = ff_w1;  j = i - 49152; }
        else                 { srcp = ff_w2;  j = i - 114688; }
        wblob[i] = f2b(load_in(srcp, j, isbf));
    } else if (i < 180992) {
        int k = i - 180224;
        const void* srcp; int j;
        if (k < 128)      { srcp = attn;  j = k; }
        else if (k < 640) { srcp = ff_b1; j = k - 128; }
        else              { srcp = ff_b2; j = k - 640; }
        fblob[k] = load_in(srcp, j, isbf);
    }
}

// ---------------- graph build ----------------
__global__ void degree_k(const int* __restrict__ src, const int* __restrict__ dst,
                         int* in_cnt, int* out_cnt, int E) {
    int i = blockIdx.x * blockDim.x + threadIdx.x;
    if (i < E) {
        atomicAdd(&in_cnt[dst[i]], 1);
        atomicAdd(&out_cnt[src[i]], 1);
    }
}

__global__ void scan1_k(const int* __restrict__ cnt, int* partial, int* blk_sum, int N) {
    __shared__ int sh[256];
    int t = threadIdx.x;
    int i = blockIdx.x * 256 + t;
    int c = (i < N) ? cnt[i] : 0;
    sh[t] = c;
    __syncthreads();
    for (int o = 1; o < 256; o <<= 1) {
        int v = (t >= o) ? sh[t - o] : 0;
        __syncthreads();
        sh[t] += v;
        __syncthreads();
    }
    if (i < N) partial[i] = sh[t] - c;
    if (t == 255) blk_sum[blockIdx.x] = sh[255];
}

__global__ void scan2_k(const int* __restrict__ blk_sum, int* blk_off, int nb,
                        int* row_ptr, int N) {
    __shared__ int sh[256];
    int t = threadIdx.x;
    if (nb <= 256) {
        int v = (t < nb) ? blk_sum[t] : 0;
        sh[t] = v;
        __syncthreads();
        for (int o = 1; o < 256; o <<= 1) {
            int u = (t >= o) ? sh[t - o] : 0;
            __syncthreads();
            sh[t] += u;
            __syncthreads();
        }
        if (t < nb) blk_off[t] = sh[t] - v;
        if (t == 255) row_ptr[N] = sh[255];
    } else if (t == 0) {
        int run = 0;
        for (int b = 0; b < nb; ++b) { blk_off[b] = run; run += blk_sum[b]; }
        row_ptr[N] = run;
    }
}

__global__ void scan3_norms_k(const int* __restrict__ partial, const int* __restrict__ blk_off,
                              const int* __restrict__ cnt_in, const int* __restrict__ cnt_out,
                              int* row_ptr, float* head_norm, float* tail_norm,
                              float* log_in, int N) {
    int i = blockIdx.x * 256 + threadIdx.x;
    if (i >= N) return;
    row_ptr[i] = partial[i] + blk_off[blockIdx.x];
    float id = fmaxf((float)cnt_in[i], 1.0f);
    float od = fmaxf((float)cnt_out[i], 1.0f);
    head_norm[i] = rsqrtf(od);
    tail_norm[i] = sqrtf(id);
    log_in[i] = log1pf(id);
}

__global__ void scatter_k(const int* __restrict__ src, const int* __restrict__ dst,
                          const int* __restrict__ row_ptr, int* cursor,
                          int* csr_src, int E) {
    int i = blockIdx.x * blockDim.x + threadIdx.x;
    if (i < E) {
        int d = dst[i];
        int p = row_ptr[d] + atomicAdd(&cursor[d], 1);
        csr_src[p] = src[i];
    }
}

// ---------------- LayerNorms ----------------
__global__ void ln1_k(const void* __restrict__ x, const void* __restrict__ g,
                      const void* __restrict__ b, const int* __restrict__ flag,
                      __hip_bfloat16* __restrict__ y, int N) {
    int w = blockIdx.x * (blockDim.x >> 6) + (threadIdx.x >> 6);
    if (w >= N) return;
    int isbf = flag[0];
    int t = threadIdx.x & 63;
    float v0 = load_in(x, (size_t)w * F + t, isbf);
    float v1 = load_in(x, (size_t)w * F + t + 64, isbf);
    float s = v0 + v1, sq = v0 * v0 + v1 * v1;
    for (int m = 1; m < 64; m <<= 1) { s += __shfl_xor(s, m, 64); sq += __shfl_xor(sq, m, 64); }
    float mu = s * (1.0f / F);
    float var = fmaxf(sq * (1.0f / F) - mu * mu, 0.0f);
    float r = rsqrtf(var + 1e-5f);
    y[(size_t)w * F + t]      = f2b((v0 - mu) * r * load_in(g, t, isbf) + load_in(b, t, isbf));
    y[(size_t)w * F + t + 64] = f2b((v1 - mu) * r * load_in(g, t + 64, isbf) + load_in(b, t + 64, isbf));
}

__global__ void ln2_k(const float* __restrict__ x, const void* __restrict__ g,
                      const void* __restrict__ b, const int* __restrict__ flag,
                      __hip_bfloat16* __restrict__ y, int N) {
    int w = blockIdx.x * (blockDim.x >> 6) + (threadIdx.x >> 6);
    if (w >= N) return;
    int isbf = flag[0];
    int t = threadIdx.x & 63;
    float v0 = x[(size_t)w * F + t], v1 = x[(size_t)w * F + t + 64];
    float s = v0 + v1, sq = v0 * v0 + v1 * v1;
    for (int m = 1; m < 64; m <<= 1) { s += __shfl_xor(s, m, 64); sq += __shfl_xor(sq, m, 64); }
    float mu = s * (1.0f / F);
    float var = fmaxf(sq * (1.0f / F) - mu * mu, 0.0f);
    float r = rsqrtf(var + 1e-5f);
    y[(size_t)w * F + t]      = f2b((v0 - mu) * r * load_in(g, t, isbf) + load_in(b, t, isbf));
    y[(size_t)w * F + t + 64] = f2b((v1 - mu) * r * load_in(g, t + 64, isbf) + load_in(b, t + 64, isbf));
}

// ---------------- projection GEMM v2: X + W staged in LDS (coalesced), frags via ds_read ----------------
__global__ void proj_gemm_k(const __hip_bfloat16* __restrict__ X,
                            const __hip_bfloat16* __restrict__ Wall,   // wh|wt|we blob
                            const float* __restrict__ head_norm,
                            __hip_bfloat16* __restrict__ fh,
                            __hip_bfloat16* __restrict__ ft,
                            uint32* __restrict__ fe_bf, int N) {
    __shared__ __align__(16) char smem[2 * 64 * W1_STRIDE * 2];   // lx 17408 + lw 17408 = 34816
    __hip_bfloat16* lx = (__hip_bfloat16*)smem;
    __hip_bfloat16* lw = (__hip_bfloat16*)(smem + 64 * W1_STRIDE * 2);
    float* eps = (float*)smem;   // 64*68*4 = 17408, reused after compute
    int tid = threadIdx.x;
    int wv = tid >> 6, lane = tid & 63;
    int lr = lane & 15, quad = lane >> 4;
    int bm = blockIdx.x * 64;
    int g = blockIdx.y;
    int wsel = g >> 1;
    int wcb = (g & 1) * 64;
    // stage X rows [bm, bm+64) (contiguous 16 KB, clamp rows >= N to row N-1... safe: read within array)
    {
        const __hip_bfloat16* xs = X + (size_t)bm * F;
        size_t maxe = (size_t)N * F;
#pragma unroll
        for (int i = 0; i < 4; ++i) {
            int idx = i * 2048 + tid * 8;
            int n = idx >> 7, k = idx & 127;
            size_t gi = (size_t)bm * F + idx;
            uint4 v = (gi + 8 <= maxe) ? *(const uint4*)(xs + idx)
                                       : *(const uint4*)(X + maxe - 8);
            *(uint4*)&lx[n * W1_STRIDE + k] = v;
        }
        // stage W block rows [wsel*128 + wcb, +64) (contiguous 16 KB)
        const __hip_bfloat16* ws = Wall + ((size_t)wsel * F + wcb) * F;
#pragma unroll
        for (int i = 0; i < 4; ++i) {
            int idx = i * 2048 + tid * 8;
            int n = idx >> 7, k = idx & 127;
            *(uint4*)&lw[n * W1_STRIDE + k] = *(const uint4*)(ws + idx);
        }
    }
    __syncthreads();
    f32x4 acc[4] = {{0,0,0,0},{0,0,0,0},{0,0,0,0},{0,0,0,0}};
#pragma unroll
    for (int ks = 0; ks < 4; ++ks) {
        bf16x8 a = *reinterpret_cast<const bf16x8*>(&lx[(wv * 16 + lr) * W1_STRIDE + ks * 32 + quad * 8]);
#pragma unroll
        for (int j = 0; j < 4; ++j) {
            bf16x8 bb = *reinterpret_cast<const bf16x8*>(&lw[(j * 16 + lr) * W1_STRIDE + ks * 32 + quad * 8]);
            acc[j] = __builtin_amdgcn_mfma_f32_16x16x32_bf16(a, bb, acc[j], 0, 0, 0);
        }
    }
    __syncthreads();   // lx/lw dead; eps reuse
    int rl = wv * 16 + quad * 4;
#pragma unroll
    for (int j = 0; j < 4; ++j)
#pragma unroll
        for (int r = 0; r < 4; ++r)
            eps[(rl + r) * LDS_STRIDE + j * 16 + lr] = acc[j][r];
    __syncthreads();
    int tr = tid >> 4, tc = (tid & 15) * 4;
#pragma unroll
    for (int p = 0; p < 4; ++p) {
        int row_l = p * 16 + tr;
        int grow = bm + row_l;
        if (grow >= N) continue;
        float4 v = *(const float4*)&eps[row_l * LDS_STRIDE + tc];
        float hn = head_norm[grow];
        v.x *= hn; v.y *= hn; v.z *= hn; v.w *= hn;
        size_t idx = (size_t)grow * F + wcb + tc;
        uint2 u; u.x = packbf2(v.x, v.y); u.y = packbf2(v.z, v.w);
        __hip_bfloat16* dstp = (wsel == 0) ? fh : (wsel == 1) ? ft : (__hip_bfloat16*)fe_bf;
        *(uint2*)&dstp[idx] = u;
    }
}

// ---------------- fused edge attention + softmax (16 lanes/edge, 4 edges/iter) ----------------
__global__ void attn_soft_k(const int* __restrict__ csr_src, const int* __restrict__ row_ptr,
                            const uint32* __restrict__ fh2, const uint32* __restrict__ ft2,
                            const float* __restrict__ attn_f, const float* __restrict__ log_in,
                            float* __restrict__ e_buf, float* __restrict__ inv_arr, int N) {
    int w = blockIdx.x * (blockDim.x >> 6) + (threadIdx.x >> 6);
    if (w >= N) return;
    int t = threadIdx.x & 63;
    int g = t >> 4, j = t & 15;
    int b = row_ptr[w], e = row_ptr[w + 1];
    uint4 fr = ((const uint4*)ft2)[(size_t)w * 16 + j];
    float ftf[8] = {bflo(fr.x), bfhi(fr.x), bflo(fr.y), bfhi(fr.y),
                    bflo(fr.z), bfhi(fr.z), bflo(fr.w), bfhi(fr.w)};
    float at[8];
#pragma unroll
    for (int k = 0; k < 8; ++k) at[k] = attn_f[8 * j + k];
    float scale = log_in[w] * (1.0f / 16.0f);
    float m = -1e30f;
    for (int p0 = b; p0 < e; p0 += 8) {
        int pa = p0 + g, pb = p0 + 4 + g;
        bool oka = pa < e, okb = pb < e;
        int sa = csr_src[oka ? pa : b];
        int sb = csr_src[okb ? pb : b];
        uint4 ga = ((const uint4*)fh2)[(size_t)sa * 16 + j];
        uint4 gb = ((const uint4*)fh2)[(size_t)sb * 16 + j];
        float ra = edge_dot(ga, ftf, at);
        float rb = edge_dot(gb, ftf, at);
        ra += __shfl_xor(ra, 1, 64);
        rb += __shfl_xor(rb, 1, 64);
        float la = ra * scale, lb = rb * scale;
        if (oka) { if (!(j & 1)) e_buf[(size_t)pa * 8 + (j >> 1)] = la; m = fmaxf(m, la); }
        if (okb) { if (!(j & 1)) e_buf[(size_t)pb * 8 + (j >> 1)] = lb; m = fmaxf(m, lb); }
    }
    m = fmaxf(m, __shfl_xor(m, 16, 64));
    m = fmaxf(m, __shfl_xor(m, 32, 64));
    float mh = __shfl(m, (t & 7) * 2, 64);
    float sum = 0.f;
    for (size_t base = (size_t)b * 8 + t; base < (size_t)e * 8; base += 64) {
        float ex = expf(e_buf[base] - mh);
        e_buf[base] = ex;
        sum += ex;
    }
    sum += __shfl_xor(sum, 8, 64);
    sum += __shfl_xor(sum, 16, 64);
    sum += __shfl_xor(sum, 32, 64);
    float inv = 1.0f / fmaxf(sum, 1e-30f);
    if (t < 8) inv_arr[(size_t)w * 8 + t] = inv;
}

// ---------------- diffusion hop (32 lanes/edge, 2 edges/iter, batch 8) ----------------
__global__ void hop_k(const uint32* __restrict__ gsrc2, const float* __restrict__ e_exp,
                      const float* __restrict__ inv_arr,
                      const int* __restrict__ csr_src, const int* __restrict__ row_ptr,
                      const float* __restrict__ tail_norm, const float* __restrict__ head_norm,
                      const uint32* __restrict__ fe_bf, const void* __restrict__ feat,
                      const int* __restrict__ flag,
                      uint32* __restrict__ out_bf, float* __restrict__ out_f32,
                      int last, int N) {
    int w = blockIdx.x * (blockDim.x >> 6) + (threadIdx.x >> 6);
    if (w >= N) return;
    int t = threadIdx.x & 63;
    int sl = t >> 5, l = t & 31;
    int h = l >> 2;
    int b = row_ptr[w], e = row_ptr[w + 1];
    float inv = inv_arr[(size_t)w * 8 + h];
    float a0 = 0.f, a1 = 0.f, a2 = 0.f, a3 = 0.f;
    int p = b;
    for (; p + 8 <= e; p += 8) {
        int pe[4]; int s[4]; float av[4]; uint2 gg[4];
#pragma unroll
        for (int i = 0; i < 4; ++i) pe[i] = p + 2 * i + sl;
#pragma unroll
        for (int i = 0; i < 4; ++i) s[i] = csr_src[pe[i]];
#pragma unroll
        for (int i = 0; i < 4; ++i) av[i] = e_exp[(size_t)pe[i] * 8 + h];
#pragma unroll
        for (int i = 0; i < 4; ++i) gg[i] = ((const uint2*)gsrc2)[(size_t)s[i] * 32 + l];
#pragma unroll
        for (int i = 0; i < 4; ++i) {
            a0 += bflo(gg[i].x) * av[i]; a1 += bfhi(gg[i].x) * av[i];
            a2 += bflo(gg[i].y) * av[i]; a3 += bfhi(gg[i].y) * av[i];
        }
    }
    if (p < e) {
        int pe[4]; int s[4]; float av[4]; uint2 gg[4]; bool ok[4];
#pragma unroll
        for (int i = 0; i < 4; ++i) {
            int q = p + 2 * i + sl;
            ok[i] = q < e;
            pe[i] = ok[i] ? q : b;
        }
#pragma unroll
        for (int i = 0; i < 4; ++i) s[i] = csr_src[pe[i]];
#pragma unroll
        for (int i = 0; i < 4; ++i) av[i] = ok[i] ? e_exp[(size_t)pe[i] * 8 + h] : 0.f;
#pragma unroll
        for (int i = 0; i < 4; ++i) gg[i] = ((const uint2*)gsrc2)[(size_t)s[i] * 32 + l];
#pragma unroll
        for (int i = 0; i < 4; ++i) {
            a0 += bflo(gg[i].x) * av[i]; a1 += bfhi(gg[i].x) * av[i];
            a2 += bflo(gg[i].y) * av[i]; a3 += bfhi(gg[i].y) * av[i];
        }
    }
    a0 += __shfl_xor(a0, 32, 64);
    a1 += __shfl_xor(a1, 32, 64);
    a2 += __shfl_xor(a2, 32, 64);
    a3 += __shfl_xor(a3, 32, 64);
    if (t < 32) {
        float tl = tail_norm[w] * 0.9f * inv;
        uint2 feu = ((const uint2*)fe_bf)[(size_t)w * 32 + l];
        float r0 = tl * a0 + 0.1f * bflo(feu.x);
        float r1 = tl * a1 + 0.1f * bfhi(feu.x);
        float r2 = tl * a2 + 0.1f * bflo(feu.y);
        float r3 = tl * a3 + 0.1f * bfhi(feu.y);
        if (last) {
            int isbf = flag[0];
            float4 o;
            if (isbf) {
                uint2 fu = ((const uint2*)feat)[(size_t)w * 32 + l];
                o.x = r0 + bflo(fu.x); o.y = r1 + bfhi(fu.x);
                o.z = r2 + bflo(fu.y); o.w = r3 + bfhi(fu.y);
            } else {
                float4 fv = ((const float4*)feat)[(size_t)w * 32 + l];
                o.x = r0 + fv.x; o.y = r1 + fv.y; o.z = r2 + fv.z; o.w = r3 + fv.w;
            }
            ((float4*)out_f32)[(size_t)w * 32 + l] = o;
        } else {
            float hn = head_norm[w];
            uint2 u;
            u.x = packbf2(r0 * hn, r1 * hn);
            u.y = packbf2(r2 * hn, r3 * hn);
            ((uint2*)out_bf)[(size_t)w * 32 + l] = u;
        }
    }
}

// ---------------- FUSED FFN v3: weights staged in LDS per chunk (coalesced) ----------------
__global__ __launch_bounds__(256, 2)
void ffn_fused_k(const __hip_bfloat16* __restrict__ Y, const __hip_bfloat16* __restrict__ W1,
                 const __hip_bfloat16* __restrict__ W2, const float* __restrict__ b1f,
                 const float* __restrict__ b2f, const float* __restrict__ rst,
                 const int* __restrict__ flag, void* __restrict__ out, int N) {
    // layout: lw1 17408 | lw2 18432 | tb 9216  = 45056 B; eps (33792) aliases from 0
    __shared__ __align__(16) char smem[45056];
    __hip_bfloat16* lw1 = (__hip_bfloat16*)smem;                 // 64 x W1_STRIDE
    __hip_bfloat16* lw2 = (__hip_bfloat16*)(smem + 17408);       // 128 x W2_STRIDE
    __hip_bfloat16* tb  = (__hip_bfloat16*)(smem + 35840);       // 4 waves x 16 x TB_STRIDE
    float* eps = (float*)smem;
    int tid = threadIdx.x;
    int wv = tid >> 6, lane = tid & 63;
    int lr = lane & 15, quad = lane >> 4;
    int bm = blockIdx.x * 64;
    int row_a = bm + wv * 16 + lr;
    if (row_a >= N) row_a = N - 1;
    bf16x8 ay[4];
    {
        const __hip_bfloat16* yr = Y + (size_t)row_a * F + quad * 8;
#pragma unroll
        for (int ks = 0; ks < 4; ++ks) ay[ks] = *reinterpret_cast<const bf16x8*>(yr + ks * 32);
    }
    f32x4 o[8];
#pragma unroll
    for (int j = 0; j < 8; ++j) o[j] = (f32x4){0,0,0,0};
    __hip_bfloat16* tbuf = tb + wv * (16 * TB_STRIDE);
    for (int c = 0; c < 8; ++c) {
        int nb0 = c * 64;
        __syncthreads();   // protect lw1/lw2 reuse from prior chunk's frag reads
        // stage W1c: contiguous 8192 elems (rows nb0..nb0+63, all K)
        {
            const __hip_bfloat16* s1 = W1 + (size_t)nb0 * F;
#pragma unroll
            for (int i = 0; i < 4; ++i) {
                int idx = i * 2048 + tid * 8;
                int n = idx >> 7, k = idx & 127;
                *(uint4*)&lw1[n * W1_STRIDE + k] = *(const uint4*)(s1 + idx);
            }
            // stage W2c: rows 0..127, cols nb0..nb0+63 (128 B contiguous per row)
#pragma unroll
            for (int i = 0; i < 4; ++i) {
                int idx = i * 2048 + tid * 8;
                int r = idx >> 6, k2 = idx & 63;
                *(uint4*)&lw2[r * W2_STRIDE + k2] = *(const uint4*)(W2 + (size_t)r * 512 + nb0 + k2);
            }
        }
        __syncthreads();
        // phase A: T1c = relu(Y @ W1c^T + b1c)
        f32x4 t[4] = {{0,0,0,0},{0,0,0,0},{0,0,0,0},{0,0,0,0}};
#pragma unroll
        for (int ks = 0; ks < 4; ++ks) {
#pragma unroll
            for (int j = 0; j < 4; ++j) {
                bf16x8 bb = *reinterpret_cast<const bf16x8*>(&lw1[(j * 16 + lr) * W1_STRIDE + ks * 32 + quad * 8]);
                t[j] = __builtin_amdgcn_mfma_f32_16x16x32_bf16(ay[ks], bb, t[j], 0, 0, 0);
            }
        }
#pragma unroll
        for (int j = 0; j < 4; ++j) {
            float bias = b1f[nb0 + 16 * j + lr];
#pragma unroll
            for (int r = 0; r < 4; ++r) {
                float v = fmaxf(t[j][r] + bias, 0.f);
                tbuf[(quad * 4 + r) * TB_STRIDE + j * 16 + lr] = f2b(v);
            }
        }
        // phase B: o += T1c @ W2c^T (A from wave-private LDS, B from staged LDS)
#pragma unroll
        for (int ks2 = 0; ks2 < 2; ++ks2) {
            bf16x8 at = *reinterpret_cast<const bf16x8*>(&tbuf[lr * TB_STRIDE + ks2 * 32 + quad * 8]);
#pragma unroll
            for (int j2 = 0; j2 < 8; ++j2) {
                bf16x8 bb = *reinterpret_cast<const bf16x8*>(&lw2[(j2 * 16 + lr) * W2_STRIDE + ks2 * 32 + quad * 8]);
                o[j2] = __builtin_amdgcn_mfma_f32_16x16x32_bf16(at, bb, o[j2], 0, 0, 0);
            }
        }
    }
    __syncthreads();   // lw/tb dead; eps reuse
    int rl = wv * 16 + quad * 4;
#pragma unroll
    for (int j = 0; j < 8; ++j)
#pragma unroll
        for (int r = 0; r < 4; ++r)
            eps[(rl + r) * 132 + j * 16 + lr] = o[j][r];
    __syncthreads();
    int isbf = flag[0];
#pragma unroll
    for (int p = 0; p < 8; ++p) {
        int idx = p * 1024 + tid * 4;
        int row_l = idx >> 7, col = idx & 127;
        int grow = bm + row_l;
        if (grow >= N) continue;
        float4 v = *(const float4*)&eps[row_l * 132 + col];
        float4 bias = *(const float4*)&b2f[col];
        float4 rv = *(const float4*)&rst[(size_t)grow * F + col];
        v.x += bias.x + rv.x; v.y += bias.y + rv.y;
        v.z += bias.z + rv.z; v.w += bias.w + rv.w;
        size_t gidx = (size_t)grow * F + col;
        if (isbf) {
            uint2 u; u.x = packbf2(v.x, v.y); u.y = packbf2(v.z, v.w);
            *(uint2*)&((__hip_bfloat16*)out)[gidx] = u;
        } else {
            *(float4*)&((float*)out)[gidx] = v;
        }
    }
}

extern "C" void kernel_launch(void* const* d_in, const int* in_sizes, int n_in,
                              void* d_out, int out_size, void* d_ws, size_t ws_size,
                              hipStream_t stream) {
    if (n_in < 15) return;
    const void* feat = d_in[0];
    const int* src = (const int*)d_in[1];
    const int* dst = (const int*)d_in[2];
    const void* w_head = d_in[3];
    const void* w_tail = d_in[4];
    const void* w_ent  = d_in[5];
    const void* attn   = d_in[6];
    const void* ln1_g  = d_in[7];
    const void* ln1_b  = d_in[8];
    const void* ln2_g  = d_in[9];
    const void* ln2_b  = d_in[10];
    const void* ff_w1  = d_in[11];
    const void* ff_b1  = d_in[12];
    const void* ff_w2  = d_in[13];
    const void* ff_b2  = d_in[14];

    const int N = in_sizes[0] / F;
    const int E = in_sizes[1];
    (void)out_size;

    char* base = (char*)d_ws;
    size_t off = 0;
    auto alloc = [&](size_t bytes) -> void* {
        void* r = base + off;
        off += (bytes + 255) & ~(size_t)255;
        return r;
    };
    int* cnt3      = (int*)alloc((size_t)3 * N * 4);
    int* in_cnt = cnt3, * out_cnt = cnt3 + N, * cursor = cnt3 + 2 * N;
    int* row_ptr   = (int*)alloc((size_t)(N + 1) * 4);
    int* partial   = (int*)alloc((size_t)N * 4);
    int* blk_sum   = (int*)alloc((size_t)1024 * 4);
    int* blk_off   = (int*)alloc((size_t)1024 * 4);
    int* flag      = (int*)alloc(256);
    float* head_norm = (float*)alloc((size_t)N * 4);
    float* tail_norm = (float*)alloc((size_t)N * 4);
    float* log_in    = (float*)alloc((size_t)N * 4);
    float* inv_arr   = (float*)alloc((size_t)N * 8 * 4);
    int* csr_src   = (int*)alloc((size_t)E * 4);
    __hip_bfloat16* wh_bf = (__hip_bfloat16*)alloc((size_t)F * F * 2);   // blob: wh|wt|we|w1|w2
    __hip_bfloat16* wt_bf = (__hip_bfloat16*)alloc((size_t)F * F * 2);
    __hip_bfloat16* we_bf = (__hip_bfloat16*)alloc((size_t)F * F * 2);
    __hip_bfloat16* w1_bf = (__hip_bfloat16*)alloc((size_t)512 * F * 2);
    __hip_bfloat16* w2_bf = (__hip_bfloat16*)alloc((size_t)F * 512 * 2);
    float* attn_f    = (float*)alloc((size_t)F * 4);
    float* b1f       = (float*)alloc((size_t)512 * 4);
    float* b2f_      = (float*)alloc((size_t)F * 4);
    __hip_bfloat16* x_bf = (__hip_bfloat16*)alloc((size_t)N * F * 2);
    __hip_bfloat16* fh   = (__hip_bfloat16*)alloc((size_t)N * F * 2);
    __hip_bfloat16* ftb  = (__hip_bfloat16*)alloc((size_t)N * F * 2);
    float* e_a = (float*)alloc((size_t)E * 8 * 4);
    uint32* fe_bf = (uint32*)alloc((size_t)N * F * 2);
    uint32* hA_bf = (uint32*)alloc((size_t)N * F * 2);
    uint32* hB_bf = (uint32*)alloc((size_t)N * F * 2);
    float* rst = (float*)alloc((size_t)N * F * 4);
    __hip_bfloat16* y_bf = (__hip_bfloat16*)hA_bf;
    (void)wt_bf; (void)we_bf;
    if (off > ws_size) return;

    const int Mb = (N + 63) / 64;
    const int nodeBlocks = (N + 3) / 4;
    const int nb = (N + 255) / 256;

    detect_k<<<1, 256, 0, stream>>>((const uint32*)feat, flag);
    cvt_all_k<<<(180992 + 255) / 256, 256, 0, stream>>>(w_head, w_tail, w_ent, ff_w1, ff_w2,
                                                        attn, ff_b1, ff_b2, flag, wh_bf, attn_f);

    hipMemsetAsync(cnt3, 0, (size_t)3 * N * 4, stream);
    degree_k<<<(E + 255) / 256, 256, 0, stream>>>(src, dst, in_cnt, out_cnt, E);
    scan1_k<<<nb, 256, 0, stream>>>(in_cnt, partial, blk_sum, N);
    scan2_k<<<1, 256, 0, stream>>>(blk_sum, blk_off, nb, row_ptr, N);
    scan3_norms_k<<<nb, 256, 0, stream>>>(partial, blk_off, in_cnt, out_cnt,
                                          row_ptr, head_norm, tail_norm, log_in, N);
    scatter_k<<<(E + 255) / 256, 256, 0, stream>>>(src, dst, row_ptr, cursor, csr_src, E);

    ln1_k<<<nodeBlocks, 256, 0, stream>>>(feat, ln1_g, ln1_b, flag, x_bf, N);
    proj_gemm_k<<<dim3(Mb, 6), 256, 0, stream>>>(x_bf, wh_bf, head_norm, fh, ftb, fe_bf, N);

    attn_soft_k<<<nodeBlocks, 256, 0, stream>>>(csr_src, row_ptr, (const uint32*)fh,
                                                (const uint32*)ftb, attn_f, log_in,
                                                e_a, inv_arr, N);

    const uint32* gsrc = fe_bf;
    uint32* bufs[2] = {hA_bf, hB_bf};
    for (int hop = 0; hop < HOPS; ++hop) {
        int last = (hop == HOPS - 1);
        uint32* dst_bf = last ? nullptr : bufs[hop & 1];
        hop_k<<<nodeBlocks, 256, 0, stream>>>(gsrc, e_a, inv_arr, csr_src, row_ptr, tail_norm,
                                              head_norm, fe_bf, feat, flag, dst_bf, rst, last, N);
        if (!last) gsrc = dst_bf;
    }

    ln2_k<<<nodeBlocks, 256, 0, stream>>>(rst, ln2_g, ln2_b, flag, y_bf, N);
    ffn_fused_k<<<Mb, 256, 0, stream>>>(y_bf, w1_bf, w2_bf, b1f, b2f_, rst, flag, d_out, N);
}

// Round 11
// 467.815 us; speedup vs baseline: 1.2343x; 1.0098x over previous
//
#include <hip/hip_runtime.h>
#include <hip/hip_bf16.h>

typedef __attribute__((ext_vector_type(8))) short bf16x8;
typedef __attribute__((ext_vector_type(4))) float f32x4;
typedef unsigned int uint32;

#define F 128
#define HOPS 5
#define LDS_STRIDE 68
#define W1_STRIDE 136
#define W2_STRIDE 72
#define TB_STRIDE 72

__device__ __forceinline__ float b2f(__hip_bfloat16 h) { return __bfloat162float(h); }
__device__ __forceinline__ __hip_bfloat16 f2b(float f) { return __float2bfloat16(f); }

__device__ __forceinline__ float load_in(const void* p, size_t i, int isbf) {
    return isbf ? __bfloat162float(((const __hip_bfloat16*)p)[i]) : ((const float*)p)[i];
}

__device__ __forceinline__ float bflo(uint32 u) { union { uint32 i; float f; } v; v.i = u << 16; return v.f; }
__device__ __forceinline__ float bfhi(uint32 u) { union { uint32 i; float f; } v; v.i = u & 0xffff0000u; return v.f; }
__device__ __forceinline__ uint32 packbf2(float a, float b) {
    __hip_bfloat16 ha = f2b(a), hb = f2b(b);
    unsigned short ua = *(unsigned short*)&ha, ub = *(unsigned short*)&hb;
    return ((uint32)ub << 16) | ua;
}

__device__ __forceinline__ float edge_dot(uint4 gv, const float* ftf, const float* at) {
    float acc = 0.f;
    uint32 us[4] = {gv.x, gv.y, gv.z, gv.w};
    #pragma unroll
    for (int k = 0; k < 4; ++k) {
        float f0 = bflo(us[k]) * ftf[2 * k];
        float f1 = bfhi(us[k]) * ftf[2 * k + 1];
        f0 = fmaxf(f0, 0.2f * f0);
        f1 = fmaxf(f1, 0.2f * f1);
        acc = fmaf(f0, at[2 * k], acc);
        acc = fmaf(f1, at[2 * k + 1], acc);
    }
    return acc;
}

// ---------------- dtype detection ----------------
__global__ void detect_k(const uint32* __restrict__ w, int* flag) {
    __shared__ int cnt[256];
    int t = threadIdx.x;
    uint32 x = w[t * 97];
    int e_low = (x >> 7) & 0xFF;
    cnt[t] = (e_low >= 110 && e_low <= 135) ? 1 : 0;
    __syncthreads();
    for (int s = 128; s > 0; s >>= 1) {
        if (t < s) cnt[t] += cnt[t + s];
        __syncthreads();
    }
    if (t == 0) flag[0] = (cnt[0] >= 160) ? 1 : 0;
}

// ---------------- fused weight/bias conversion ----------------
__global__ void cvt_all_k(const void* __restrict__ w_head, const void* __restrict__ w_tail,
                          const void* __restrict__ w_ent, const void* __restrict__ ff_w1,
                          const void* __restrict__ ff_w2, const void* __restrict__ attn,
                          const void* __restrict__ ff_b1, const void* __restrict__ ff_b2,
                          const int* __restrict__ flag,
                          __hip_bfloat16* __restrict__ wblob, float* __restrict__ fblob) {
    int i = blockIdx.x * blockDim.x + threadIdx.x;
    int isbf = flag[0];
    if (i < 180224) {
        const void* srcp; int j;
        if (i < 16384)       { srcp = w_head; j = i; }
        else if (i < 32768)  { srcp = w_tail; j = i - 16384; }
        else if (i < 49152)  { srcp = w_ent;  j = i - 32768; }
        else if (i < 114688) { srcp = ff_w1;  j = i - 49152; }
        else                 { srcp = ff_w2;  j = i - 114688; }
        wblob[i] = f2b(load_in(srcp, j, isbf));
    } else if (i < 180992) {
        int k = i - 180224;
        const void* srcp; int j;
        if (k < 128)      { srcp = attn;  j = k; }
        else if (k < 640) { srcp = ff_b1; j = k - 128; }
        else              { srcp = ff_b2; j = k - 640; }
        fblob[k] = load_in(srcp, j, isbf);
    }
}

// ---------------- graph build: 8-slice histograms (slice = blockIdx & 7 ~ XCD) ----------------
__global__ void degree_k(const int* __restrict__ src, const int* __restrict__ dst,
                         int* in8, int* out8, int E, int N) {
    int i = blockIdx.x * blockDim.x + threadIdx.x;
    int slice = blockIdx.x & 7;
    if (i < E) {
        atomicAdd(&in8[slice * N + dst[i]], 1);
        atomicAdd(&out8[slice * N + src[i]], 1);
    }
}

__global__ void scan1_k(const int* __restrict__ in8, int* partial, int* blk_sum, int N) {
    __shared__ int sh[256];
    int t = threadIdx.x;
    int i = blockIdx.x * 256 + t;
    int c = 0;
    if (i < N) {
#pragma unroll
        for (int s = 0; s < 8; ++s) c += in8[s * N + i];
    }
    sh[t] = c;
    __syncthreads();
    for (int o = 1; o < 256; o <<= 1) {
        int v = (t >= o) ? sh[t - o] : 0;
        __syncthreads();
        sh[t] += v;
        __syncthreads();
    }
    if (i < N) partial[i] = sh[t] - c;
    if (t == 255) blk_sum[blockIdx.x] = sh[255];
}

__global__ void scan2_k(const int* __restrict__ blk_sum, int* blk_off, int nb,
                        int* row_ptr, int N) {
    __shared__ int sh[256];
    int t = threadIdx.x;
    if (nb <= 256) {
        int v = (t < nb) ? blk_sum[t] : 0;
        sh[t] = v;
        __syncthreads();
        for (int o = 1; o < 256; o <<= 1) {
            int u = (t >= o) ? sh[t - o] : 0;
            __syncthreads();
            sh[t] += u;
            __syncthreads();
        }
        if (t < nb) blk_off[t] = sh[t] - v;
        if (t == 255) row_ptr[N] = sh[255];
    } else if (t == 0) {
        int run = 0;
        for (int b = 0; b < nb; ++b) { blk_off[b] = run; run += blk_sum[b]; }
        row_ptr[N] = run;
    }
}

// phase3: row_ptr, per-slice offsets, node norms
__global__ void scan3_norms_k(const int* __restrict__ partial, const int* __restrict__ blk_off,
                              const int* __restrict__ in8, const int* __restrict__ out8,
                              int* row_ptr, int* soff, float* head_norm, float* tail_norm,
                              float* log_in, int N) {
    int i = blockIdx.x * 256 + threadIdx.x;
    if (i >= N) return;
    row_ptr[i] = partial[i] + blk_off[blockIdx.x];
    int run = 0;
#pragma unroll
    for (int s = 0; s < 8; ++s) { soff[s * N + i] = run; run += in8[s * N + i]; }
    int od = 0;
#pragma unroll
    for (int s = 0; s < 8; ++s) od += out8[s * N + i];
    float id = fmaxf((float)run, 1.0f);
    float odf = fmaxf((float)od, 1.0f);
    head_norm[i] = rsqrtf(odf);
    tail_norm[i] = sqrtf(id);
    log_in[i] = log1pf(id);
}

__global__ void scatter_k(const int* __restrict__ src, const int* __restrict__ dst,
                          const int* __restrict__ row_ptr, const int* __restrict__ soff,
                          int* cursor8, int* csr_src, int E, int N) {
    int i = blockIdx.x * blockDim.x + threadIdx.x;
    int slice = blockIdx.x & 7;
    if (i < E) {
        int d = dst[i];
        int p = row_ptr[d] + soff[slice * N + d] + atomicAdd(&cursor8[slice * N + d], 1);
        csr_src[p] = src[i];
    }
}

// ---------------- LayerNorms ----------------
__global__ void ln1_k(const void* __restrict__ x, const void* __restrict__ g,
                      const void* __restrict__ b, const int* __restrict__ flag,
                      __hip_bfloat16* __restrict__ y, int N) {
    int w = blockIdx.x * (blockDim.x >> 6) + (threadIdx.x >> 6);
    if (w >= N) return;
    int isbf = flag[0];
    int t = threadIdx.x & 63;
    float v0 = load_in(x, (size_t)w * F + t, isbf);
    float v1 = load_in(x, (size_t)w * F + t + 64, isbf);
    float s = v0 + v1, sq = v0 * v0 + v1 * v1;
    for (int m = 1; m < 64; m <<= 1) { s += __shfl_xor(s, m, 64); sq += __shfl_xor(sq, m, 64); }
    float mu = s * (1.0f / F);
    float var = fmaxf(sq * (1.0f / F) - mu * mu, 0.0f);
    float r = rsqrtf(var + 1e-5f);
    y[(size_t)w * F + t]      = f2b((v0 - mu) * r * load_in(g, t, isbf) + load_in(b, t, isbf));
    y[(size_t)w * F + t + 64] = f2b((v1 - mu) * r * load_in(g, t + 64, isbf) + load_in(b, t + 64, isbf));
}

__global__ void ln2_k(const float* __restrict__ x, const void* __restrict__ g,
                      const void* __restrict__ b, const int* __restrict__ flag,
                      __hip_bfloat16* __restrict__ y, int N) {
    int w = blockIdx.x * (blockDim.x >> 6) + (threadIdx.x >> 6);
    if (w >= N) return;
    int isbf = flag[0];
    int t = threadIdx.x & 63;
    float v0 = x[(size_t)w * F + t], v1 = x[(size_t)w * F + t + 64];
    float s = v0 + v1, sq = v0 * v0 + v1 * v1;
    for (int m = 1; m < 64; m <<= 1) { s += __shfl_xor(s, m, 64); sq += __shfl_xor(sq, m, 64); }
    float mu = s * (1.0f / F);
    float var = fmaxf(sq * (1.0f / F) - mu * mu, 0.0f);
    float r = rsqrtf(var + 1e-5f);
    y[(size_t)w * F + t]      = f2b((v0 - mu) * r * load_in(g, t, isbf) + load_in(b, t, isbf));
    y[(size_t)w * F + t + 64] = f2b((v1 - mu) * r * load_in(g, t + 64, isbf) + load_in(b, t + 64, isbf));
}

// ---------------- projection GEMM (LDS-staged X and W) ----------------
__global__ void proj_gemm_k(const __hip_bfloat16* __restrict__ X,
                            const __hip_bfloat16* __restrict__ Wall,
                            const float* __restrict__ head_norm,
                            __hip_bfloat16* __restrict__ fh,
                            __hip_bfloat16* __restrict__ ft,
                            uint32* __restrict__ fe_bf, int N) {
    __shared__ __align__(16) char smem[2 * 64 * W1_STRIDE * 2];
    __hip_bfloat16* lx = (__hip_bfloat16*)smem;
    __hip_bfloat16* lw = (__hip_bfloat16*)(smem + 64 * W1_STRIDE * 2);
    float* eps = (float*)smem;
    int tid = threadIdx.x;
    int wv = tid >> 6, lane = tid & 63;
    int lr = lane & 15, quad = lane >> 4;
    int bm = blockIdx.x * 64;
    int g = blockIdx.y;
    int wsel = g >> 1;
    int wcb = (g & 1) * 64;
    {
        const __hip_bfloat16* xs = X + (size_t)bm * F;
        size_t maxe = (size_t)N * F;
#pragma unroll
        for (int i = 0; i < 4; ++i) {
            int idx = i * 2048 + tid * 8;
            int n = idx >> 7, k = idx & 127;
            size_t gi = (size_t)bm * F + idx;
            uint4 v = (gi + 8 <= maxe) ? *(const uint4*)(xs + idx)
                                       : *(const uint4*)(X + maxe - 8);
            *(uint4*)&lx[n * W1_STRIDE + k] = v;
        }
        const __hip_bfloat16* ws = Wall + ((size_t)wsel * F + wcb) * F;
#pragma unroll
        for (int i = 0; i < 4; ++i) {
            int idx = i * 2048 + tid * 8;
            int n = idx >> 7, k = idx & 127;
            *(uint4*)&lw[n * W1_STRIDE + k] = *(const uint4*)(ws + idx);
        }
    }
    __syncthreads();
    f32x4 acc[4] = {{0,0,0,0},{0,0,0,0},{0,0,0,0},{0,0,0,0}};
#pragma unroll
    for (int ks = 0; ks < 4; ++ks) {
        bf16x8 a = *reinterpret_cast<const bf16x8*>(&lx[(wv * 16 + lr) * W1_STRIDE + ks * 32 + quad * 8]);
#pragma unroll
        for (int j = 0; j < 4; ++j) {
            bf16x8 bb = *reinterpret_cast<const bf16x8*>(&lw[(j * 16 + lr) * W1_STRIDE + ks * 32 + quad * 8]);
            acc[j] = __builtin_amdgcn_mfma_f32_16x16x32_bf16(a, bb, acc[j], 0, 0, 0);
        }
    }
    __syncthreads();
    int rl = wv * 16 + quad * 4;
#pragma unroll
    for (int j = 0; j < 4; ++j)
#pragma unroll
        for (int r = 0; r < 4; ++r)
            eps[(rl + r) * LDS_STRIDE + j * 16 + lr] = acc[j][r];
    __syncthreads();
    int tr = tid >> 4, tc = (tid & 15) * 4;
#pragma unroll
    for (int p = 0; p < 4; ++p) {
        int row_l = p * 16 + tr;
        int grow = bm + row_l;
        if (grow >= N) continue;
        float4 v = *(const float4*)&eps[row_l * LDS_STRIDE + tc];
        float hn = head_norm[grow];
        v.x *= hn; v.y *= hn; v.z *= hn; v.w *= hn;
        size_t idx = (size_t)grow * F + wcb + tc;
        uint2 u; u.x = packbf2(v.x, v.y); u.y = packbf2(v.z, v.w);
        __hip_bfloat16* dstp = (wsel == 0) ? fh : (wsel == 1) ? ft : (__hip_bfloat16*)fe_bf;
        *(uint2*)&dstp[idx] = u;
    }
}

// ---------------- fused edge attention + softmax (16 lanes/edge, 4 edges/iter) ----------------
__global__ void attn_soft_k(const int* __restrict__ csr_src, const int* __restrict__ row_ptr,
                            const uint32* __restrict__ fh2, const uint32* __restrict__ ft2,
                            const float* __restrict__ attn_f, const float* __restrict__ log_in,
                            float* __restrict__ e_buf, float* __restrict__ inv_arr, int N) {
    int w = blockIdx.x * (blockDim.x >> 6) + (threadIdx.x >> 6);
    if (w >= N) return;
    int t = threadIdx.x & 63;
    int g = t >> 4, j = t & 15;
    int b = row_ptr[w], e = row_ptr[w + 1];
    uint4 fr = ((const uint4*)ft2)[(size_t)w * 16 + j];
    float ftf[8] = {bflo(fr.x), bfhi(fr.x), bflo(fr.y), bfhi(fr.y),
                    bflo(fr.z), bfhi(fr.z), bflo(fr.w), bfhi(fr.w)};
    float at[8];
#pragma unroll
    for (int k = 0; k < 8; ++k) at[k] = attn_f[8 * j + k];
    float scale = log_in[w] * (1.0f / 16.0f);
    float m = -1e30f;
    for (int p0 = b; p0 < e; p0 += 8) {
        int pa = p0 + g, pb = p0 + 4 + g;
        bool oka = pa < e, okb = pb < e;
        int sa = csr_src[oka ? pa : b];
        int sb = csr_src[okb ? pb : b];
        uint4 ga = ((const uint4*)fh2)[(size_t)sa * 16 + j];
        uint4 gb = ((const uint4*)fh2)[(size_t)sb * 16 + j];
        float ra = edge_dot(ga, ftf, at);
        float rb = edge_dot(gb, ftf, at);
        ra += __shfl_xor(ra, 1, 64);
        rb += __shfl_xor(rb, 1, 64);
        float la = ra * scale, lb = rb * scale;
        if (oka) { if (!(j & 1)) e_buf[(size_t)pa * 8 + (j >> 1)] = la; m = fmaxf(m, la); }
        if (okb) { if (!(j & 1)) e_buf[(size_t)pb * 8 + (j >> 1)] = lb; m = fmaxf(m, lb); }
    }
    m = fmaxf(m, __shfl_xor(m, 16, 64));
    m = fmaxf(m, __shfl_xor(m, 32, 64));
    float mh = __shfl(m, (t & 7) * 2, 64);
    float sum = 0.f;
    for (size_t base = (size_t)b * 8 + t; base < (size_t)e * 8; base += 64) {
        float ex = expf(e_buf[base] - mh);
        e_buf[base] = ex;
        sum += ex;
    }
    sum += __shfl_xor(sum, 8, 64);
    sum += __shfl_xor(sum, 16, 64);
    sum += __shfl_xor(sum, 32, 64);
    float inv = 1.0f / fmaxf(sum, 1e-30f);
    if (t < 8) inv_arr[(size_t)w * 8 + t] = inv;
}

// ---------------- diffusion hop v3: 2 nodes/wave (half-wave each), batch-8 edges ----------------
__global__ void hop_k(const uint32* __restrict__ gsrc2, const float* __restrict__ e_exp,
                      const float* __restrict__ inv_arr,
                      const int* __restrict__ csr_src, const int* __restrict__ row_ptr,
                      const float* __restrict__ tail_norm, const float* __restrict__ head_norm,
                      const uint32* __restrict__ fe_bf, const void* __restrict__ feat,
                      const int* __restrict__ flag,
                      uint32* __restrict__ out_bf, float* __restrict__ out_f32,
                      int last, int N) {
    int w = blockIdx.x * 8 + (threadIdx.x >> 5);   // 8 half-waves per 256-thr block
    if (w >= N) return;
    int l = threadIdx.x & 31;                      // features [4l, 4l+4)
    int h = l >> 2;
    int b = row_ptr[w], e = row_ptr[w + 1];
    float inv = inv_arr[(size_t)w * 8 + h];
    float a0 = 0.f, a1 = 0.f, a2 = 0.f, a3 = 0.f;
    int p = b;
    for (; p + 8 <= e; p += 8) {
        int s[8]; float av[8]; uint2 gg[8];
#pragma unroll
        for (int i = 0; i < 8; ++i) s[i] = csr_src[p + i];
#pragma unroll
        for (int i = 0; i < 8; ++i) av[i] = e_exp[(size_t)(p + i) * 8 + h];
#pragma unroll
        for (int i = 0; i < 8; ++i) gg[i] = ((const uint2*)gsrc2)[(size_t)s[i] * 32 + l];
#pragma unroll
        for (int i = 0; i < 8; ++i) {
            a0 += bflo(gg[i].x) * av[i]; a1 += bfhi(gg[i].x) * av[i];
            a2 += bflo(gg[i].y) * av[i]; a3 += bfhi(gg[i].y) * av[i];
        }
    }
    if (p < e) {
        int s[8]; float av[8]; uint2 gg[8];
#pragma unroll
        for (int i = 0; i < 8; ++i) {
            int q = p + i;
            bool ok = q < e;
            int q2 = ok ? q : b;
            s[i] = csr_src[q2];
            av[i] = ok ? e_exp[(size_t)q * 8 + h] : 0.f;
        }
#pragma unroll
        for (int i = 0; i < 8; ++i) gg[i] = ((const uint2*)gsrc2)[(size_t)s[i] * 32 + l];
#pragma unroll
        for (int i = 0; i < 8; ++i) {
            a0 += bflo(gg[i].x) * av[i]; a1 += bfhi(gg[i].x) * av[i];
            a2 += bflo(gg[i].y) * av[i]; a3 += bfhi(gg[i].y) * av[i];
        }
    }
    float tl = tail_norm[w] * 0.9f * inv;
    uint2 feu = ((const uint2*)fe_bf)[(size_t)w * 32 + l];
    float r0 = tl * a0 + 0.1f * bflo(feu.x);
    float r1 = tl * a1 + 0.1f * bfhi(feu.x);
    float r2 = tl * a2 + 0.1f * bflo(feu.y);
    float r3 = tl * a3 + 0.1f * bfhi(feu.y);
    if (last) {
        int isbf = flag[0];
        float4 o;
        if (isbf) {
            uint2 fu = ((const uint2*)feat)[(size_t)w * 32 + l];
            o.x = r0 + bflo(fu.x); o.y = r1 + bfhi(fu.x);
            o.z = r2 + bflo(fu.y); o.w = r3 + bfhi(fu.y);
        } else {
            float4 fv = ((const float4*)feat)[(size_t)w * 32 + l];
            o.x = r0 + fv.x; o.y = r1 + fv.y; o.z = r2 + fv.z; o.w = r3 + fv.w;
        }
        ((float4*)out_f32)[(size_t)w * 32 + l] = o;
    } else {
        float hn = head_norm[w];
        uint2 u;
        u.x = packbf2(r0 * hn, r1 * hn);
        u.y = packbf2(r2 * hn, r3 * hn);
        ((uint2*)out_bf)[(size_t)w * 32 + l] = u;
    }
}

// ---------------- FUSED FFN v3 (LDS-staged weights) ----------------
__global__ __launch_bounds__(256, 2)
void ffn_fused_k(const __hip_bfloat16* __restrict__ Y, const __hip_bfloat16* __restrict__ W1,
                 const __hip_bfloat16* __restrict__ W2, const float* __restrict__ b1f,
                 const float* __restrict__ b2f, const float* __restrict__ rst,
                 const int* __restrict__ flag, void* __restrict__ out, int N) {
    __shared__ __align__(16) char smem[45056];
    __hip_bfloat16* lw1 = (__hip_bfloat16*)smem;
    __hip_bfloat16* lw2 = (__hip_bfloat16*)(smem + 17408);
    __hip_bfloat16* tb  = (__hip_bfloat16*)(smem + 35840);
    float* eps = (float*)smem;
    int tid = threadIdx.x;
    int wv = tid >> 6, lane = tid & 63;
    int lr = lane & 15, quad = lane >> 4;
    int bm = blockIdx.x * 64;
    int row_a = bm + wv * 16 + lr;
    if (row_a >= N) row_a = N - 1;
    bf16x8 ay[4];
    {
        const __hip_bfloat16* yr = Y + (size_t)row_a * F + quad * 8;
#pragma unroll
        for (int ks = 0; ks < 4; ++ks) ay[ks] = *reinterpret_cast<const bf16x8*>(yr + ks * 32);
    }
    f32x4 o[8];
#pragma unroll
    for (int j = 0; j < 8; ++j) o[j] = (f32x4){0,0,0,0};
    __hip_bfloat16* tbuf = tb + wv * (16 * TB_STRIDE);
    for (int c = 0; c < 8; ++c) {
        int nb0 = c * 64;
        __syncthreads();
        {
            const __hip_bfloat16* s1 = W1 + (size_t)nb0 * F;
#pragma unroll
            for (int i = 0; i < 4; ++i) {
                int idx = i * 2048 + tid * 8;
                int n = idx >> 7, k = idx & 127;
                *(uint4*)&lw1[n * W1_STRIDE + k] = *(const uint4*)(s1 + idx);
            }
#pragma unroll
            for (int i = 0; i < 4; ++i) {
                int idx = i * 2048 + tid * 8;
                int r = idx >> 6, k2 = idx & 63;
                *(uint4*)&lw2[r * W2_STRIDE + k2] = *(const uint4*)(W2 + (size_t)r * 512 + nb0 + k2);
            }
        }
        __syncthreads();
        f32x4 t[4] = {{0,0,0,0},{0,0,0,0},{0,0,0,0},{0,0,0,0}};
#pragma unroll
        for (int ks = 0; ks < 4; ++ks) {
#pragma unroll
            for (int j = 0; j < 4; ++j) {
                bf16x8 bb = *reinterpret_cast<const bf16x8*>(&lw1[(j * 16 + lr) * W1_STRIDE + ks * 32 + quad * 8]);
                t[j] = __builtin_amdgcn_mfma_f32_16x16x32_bf16(ay[ks], bb, t[j], 0, 0, 0);
            }
        }
#pragma unroll
        for (int j = 0; j < 4; ++j) {
            float bias = b1f[nb0 + 16 * j + lr];
#pragma unroll
            for (int r = 0; r < 4; ++r) {
                float v = fmaxf(t[j][r] + bias, 0.f);
                tbuf[(quad * 4 + r) * TB_STRIDE + j * 16 + lr] = f2b(v);
            }
        }
#pragma unroll
        for (int ks2 = 0; ks2 < 2; ++ks2) {
            bf16x8 at = *reinterpret_cast<const bf16x8*>(&tbuf[lr * TB_STRIDE + ks2 * 32 + quad * 8]);
#pragma unroll
            for (int j2 = 0; j2 < 8; ++j2) {
                bf16x8 bb = *reinterpret_cast<const bf16x8*>(&lw2[(j2 * 16 + lr) * W2_STRIDE + ks2 * 32 + quad * 8]);
                o[j2] = __builtin_amdgcn_mfma_f32_16x16x32_bf16(at, bb, o[j2], 0, 0, 0);
            }
        }
    }
    __syncthreads();
    int rl = wv * 16 + quad * 4;
#pragma unroll
    for (int j = 0; j < 8; ++j)
#pragma unroll
        for (int r = 0; r < 4; ++r)
            eps[(rl + r) * 132 + j * 16 + lr] = o[j][r];
    __syncthreads();
    int isbf = flag[0];
#pragma unroll
    for (int p = 0; p < 8; ++p) {
        int idx = p * 1024 + tid * 4;
        int row_l = idx >> 7, col = idx & 127;
        int grow = bm + row_l;
        if (grow >= N) continue;
        float4 v = *(const float4*)&eps[row_l * 132 + col];
        float4 bias = *(const float4*)&b2f[col];
        float4 rv = *(const float4*)&rst[(size_t)grow * F + col];
        v.x += bias.x + rv.x; v.y += bias.y + rv.y;
        v.z += bias.z + rv.z; v.w += bias.w + rv.w;
        size_t gidx = (size_t)grow * F + col;
        if (isbf) {
            uint2 u; u.x = packbf2(v.x, v.y); u.y = packbf2(v.z, v.w);
            *(uint2*)&((__hip_bfloat16*)out)[gidx] = u;
        } else {
            *(float4*)&((float*)out)[gidx] = v;
        }
    }
}

extern "C" void kernel_launch(void* const* d_in, const int* in_sizes, int n_in,
                              void* d_out, int out_size, void* d_ws, size_t ws_size,
                              hipStream_t stream) {
    if (n_in < 15) return;
    const void* feat = d_in[0];
    const int* src = (const int*)d_in[1];
    const int* dst = (const int*)d_in[2];
    const void* w_head = d_in[3];
    const void* w_tail = d_in[4];
    const void* w_ent  = d_in[5];
    const void* attn   = d_in[6];
    const void* ln1_g  = d_in[7];
    const void* ln1_b  = d_in[8];
    const void* ln2_g  = d_in[9];
    const void* ln2_b  = d_in[10];
    const void* ff_w1  = d_in[11];
    const void* ff_b1  = d_in[12];
    const void* ff_w2  = d_in[13];
    const void* ff_b2  = d_in[14];

    const int N = in_sizes[0] / F;
    const int E = in_sizes[1];
    (void)out_size;

    char* base = (char*)d_ws;
    size_t off = 0;
    auto alloc = [&](size_t bytes) -> void* {
        void* r = base + off;
        off += (bytes + 255) & ~(size_t)255;
        return r;
    };
    int* zr        = (int*)alloc((size_t)24 * N * 4);   // in8 | out8 | cursor8 (zeroed)
    int* in8 = zr, * out8 = zr + 8 * N, * cursor8 = zr + 16 * N;
    int* soff      = (int*)alloc((size_t)8 * N * 4);
    int* row_ptr   = (int*)alloc((size_t)(N + 1) * 4);
    int* partial   = (int*)alloc((size_t)N * 4);
    int* blk_sum   = (int*)alloc((size_t)1024 * 4);
    int* blk_off   = (int*)alloc((size_t)1024 * 4);
    int* flag      = (int*)alloc(256);
    float* head_norm = (float*)alloc((size_t)N * 4);
    float* tail_norm = (float*)alloc((size_t)N * 4);
    float* log_in    = (float*)alloc((size_t)N * 4);
    float* inv_arr   = (float*)alloc((size_t)N * 8 * 4);
    int* csr_src   = (int*)alloc((size_t)E * 4);
    __hip_bfloat16* wh_bf = (__hip_bfloat16*)alloc((size_t)F * F * 2);   // blob start
    __hip_bfloat16* wt_bf = (__hip_bfloat16*)alloc((size_t)F * F * 2);
    __hip_bfloat16* we_bf = (__hip_bfloat16*)alloc((size_t)F * F * 2);
    __hip_bfloat16* w1_bf = (__hip_bfloat16*)alloc((size_t)512 * F * 2);
    __hip_bfloat16* w2_bf = (__hip_bfloat16*)alloc((size_t)F * 512 * 2);
    float* attn_f    = (float*)alloc((size_t)F * 4);
    float* b1f       = (float*)alloc((size_t)512 * 4);
    float* b2f_      = (float*)alloc((size_t)F * 4);
    __hip_bfloat16* x_bf = (__hip_bfloat16*)alloc((size_t)N * F * 2);
    __hip_bfloat16* fh   = (__hip_bfloat16*)alloc((size_t)N * F * 2);
    __hip_bfloat16* ftb  = (__hip_bfloat16*)alloc((size_t)N * F * 2);
    float* e_a = (float*)alloc((size_t)E * 8 * 4);
    uint32* fe_bf = (uint32*)alloc((size_t)N * F * 2);
    uint32* hA_bf = (uint32*)alloc((size_t)N * F * 2);
    uint32* hB_bf = (uint32*)alloc((size_t)N * F * 2);
    float* rst = (float*)alloc((size_t)N * F * 4);
    __hip_bfloat16* y_bf = (__hip_bfloat16*)hA_bf;
    (void)wt_bf; (void)we_bf;
    if (off > ws_size) return;

    const int Mb = (N + 63) / 64;
    const int nodeBlocks = (N + 3) / 4;
    const int hopBlocks = (N + 7) / 8;
    const int nb = (N + 255) / 256;

    detect_k<<<1, 256, 0, stream>>>((const uint32*)feat, flag);
    cvt_all_k<<<(180992 + 255) / 256, 256, 0, stream>>>(w_head, w_tail, w_ent, ff_w1, ff_w2,
                                                        attn, ff_b1, ff_b2, flag, wh_bf, attn_f);

    hipMemsetAsync(zr, 0, (size_t)24 * N * 4, stream);
    degree_k<<<(E + 255) / 256, 256, 0, stream>>>(src, dst, in8, out8, E, N);
    scan1_k<<<nb, 256, 0, stream>>>(in8, partial, blk_sum, N);
    scan2_k<<<1, 256, 0, stream>>>(blk_sum, blk_off, nb, row_ptr, N);
    scan3_norms_k<<<nb, 256, 0, stream>>>(partial, blk_off, in8, out8,
                                          row_ptr, soff, head_norm, tail_norm, log_in, N);
    scatter_k<<<(E + 255) / 256, 256, 0, stream>>>(src, dst, row_ptr, soff, cursor8, csr_src, E, N);

    ln1_k<<<nodeBlocks, 256, 0, stream>>>(feat, ln1_g, ln1_b, flag, x_bf, N);
    proj_gemm_k<<<dim3(Mb, 6), 256, 0, stream>>>(x_bf, wh_bf, head_norm, fh, ftb, fe_bf, N);

    attn_soft_k<<<nodeBlocks, 256, 0, stream>>>(csr_src, row_ptr, (const uint32*)fh,
                                                (const uint32*)ftb, attn_f, log_in,
                                                e_a, inv_arr, N);

    const uint32* gsrc = fe_bf;
    uint32* bufs[2] = {hA_bf, hB_bf};
    for (int hop = 0; hop < HOPS; ++hop) {
        int last = (hop == HOPS - 1);
        uint32* dst_bf = last ? nullptr : bufs[hop & 1];
        hop_k<<<hopBlocks, 256, 0, stream>>>(gsrc, e_a, inv_arr, csr_src, row_ptr, tail_norm,
                                             head_norm, fe_bf, feat, flag, dst_bf, rst, last, N);
        if (!last) gsrc = dst_bf;
    }

    ln2_k<<<nodeBlocks, 256, 0, stream>>>(rst, ln2_g, ln2_b, flag, y_bf, N);
    ffn_fused_k<<<Mb, 256, 0, stream>>>(y_bf, w1_bf, w2_bf, b1f, b2f_, rst, flag, d_out, N);
}